// Round 9
// baseline (237.615 us; speedup 1.0000x reference)
//
#include <hip/hip_runtime.h>
#include <stdint.h>

// Problem constants (fixed by reference)
#define NXc 352
#define NYc 400
#define NZc 20
#define KS  11264000          // 4*20*400*352 keys
#define WORDS 176000          // KS/64 presence words
#define NBLKS 688             // scan blocks: 256 thr x 64 keys = 16384 keys each
#define NCH 64
#define RPT 8                 // rows per lane-group in k_gather

// ws layout (bytes), total ~25.4 MB
#define OFF_A     0ull                      // byte counts / countdown cursors (11,264,000)
#define OFF_P     11264000ull               // presence bitmap, uint64[WORDS]
#define OFF_R     12672000ull               // word rank base, uint32[WORDS]
#define OFF_DESC  13376000ull               // lookback descriptors, uint64[NBLKS]
#define OFF_NU    13381504ull
#define OFF_KEYPT 13381760ull               // key per point (4,000,000)
#define OFF_IOFF  17381760ull               // CSR offsets (4,000,256)
#define OFF_PID   21381760ull               // point ids (4,000,000) -- 256-pad before

static __device__ __forceinline__ int keyof(int4 c) {
  return ((c.x * NZc + c.y) * NYc + c.z) * NXc + c.w;  // [b,z,y,x]
}

// desc packing: [63:62]=status (0 none, 1 aggregate, 2 prefix), [61:31]=pres, [30:0]=cnt
static __device__ __forceinline__ unsigned long long packd(unsigned int st, unsigned int p, unsigned int c) {
  return ((unsigned long long)st << 62) | ((unsigned long long)p << 31) | (unsigned long long)c;
}

__global__ void k_zero(uint4* __restrict__ A4, unsigned int mA,
                       uint4* __restrict__ D4, unsigned int mD,
                       float4* __restrict__ C4, unsigned int mC) {
  unsigned int i = blockIdx.x * 256 + threadIdx.x, s = gridDim.x * 256;
  uint4 z = make_uint4(0u, 0u, 0u, 0u);
  for (unsigned int j = i; j < mA; j += s) A4[j] = z;
  for (unsigned int j = i; j < mD; j += s) D4[j] = z;
  float4 m1 = make_float4(-1.f, -1.f, -1.f, -1.f);
  for (unsigned int j = i; j < mC; j += s) C4[j] = m1;   // coors padding = -1
}

// byte-packed count + cache key per point
__global__ void k_count(const int4* __restrict__ coors, unsigned int* __restrict__ A32,
                        int* __restrict__ keyPt, int n) {
  int p = blockIdx.x * 256 + threadIdx.x;
  if (p >= n) return;
  int key = keyof(coors[p]);
  keyPt[p] = key;
  atomicAdd(&A32[key >> 2], 1u << (8 * (key & 3)));
}

// Fused single-pass scan (decoupled lookback). One 64-key word per thread.
// Emits P, R, ioff[rank], out-coors[rank]; last block writes nu & ioff[nU]=n.
// Safe: all 688 blocks co-resident (2KB LDS, ~40 VGPR) => no deadlock.
__global__ void k_scan(const unsigned char* __restrict__ A,
                       unsigned long long* __restrict__ desc,
                       unsigned long long* __restrict__ P, unsigned int* __restrict__ R,
                       unsigned int* __restrict__ ioff, unsigned int* __restrict__ nu,
                       float4* __restrict__ outc, int n) {
  int b = blockIdx.x, t = threadIdx.x;
  int w = b * 256 + t;
  unsigned long long mask = 0ull;
  unsigned int uu[16];
  unsigned int pres = 0, cnt = 0;
  if (w < WORDS) {
    const uint4* aw = (const uint4*)(A + (size_t)w * 64);
#pragma unroll
    for (int q = 0; q < 4; q++) {
      uint4 v = aw[q];
      uu[q * 4 + 0] = v.x; uu[q * 4 + 1] = v.y; uu[q * 4 + 2] = v.z; uu[q * 4 + 3] = v.w;
    }
#pragma unroll
    for (int i = 0; i < 16; i++) {
      unsigned int u = uu[i];
#pragma unroll
      for (int bb = 0; bb < 4; bb++) {
        unsigned int byte = (u >> (8 * bb)) & 0xFFu;
        cnt += byte;
        if (byte) mask |= 1ull << (i * 4 + bb);
      }
    }
    pres = (unsigned int)__popcll(mask);
  }
  __shared__ unsigned int sp[256], sc[256];
  sp[t] = pres; sc[t] = cnt; __syncthreads();
  unsigned int ip = pres, ic = cnt;
  for (int o = 1; o < 256; o <<= 1) {
    unsigned int ap = (t >= o) ? sp[t - o] : 0u;
    unsigned int ac = (t >= o) ? sc[t - o] : 0u;
    __syncthreads();
    ip += ap; ic += ac;
    sp[t] = ip; sc[t] = ic; __syncthreads();
  }
  __shared__ unsigned int exc2[2];
  if (t == 0) {
    unsigned int aggP = sp[255], aggC = sc[255];
    unsigned int eP = 0, eC = 0;
    if (b == 0) {
      atomicExch(&desc[0], packd(2u, aggP, aggC));
    } else {
      atomicExch(&desc[b], packd(1u, aggP, aggC));
      int j = b - 1;
      for (;;) {
        unsigned long long d = atomicAdd(&desc[j], 0ull);   // device-scope read
        unsigned int st = (unsigned int)(d >> 62);
        if (st == 0u) continue;                              // spin
        eP += (unsigned int)((d >> 31) & 0x7FFFFFFFull);
        eC += (unsigned int)(d & 0x7FFFFFFFull);
        if (st == 2u) break;
        --j;
      }
      atomicExch(&desc[b], packd(2u, eP + aggP, eC + aggC));
    }
    exc2[0] = eP; exc2[1] = eC;
    if (b == NBLKS - 1) {
      unsigned int tot = eP + aggP;
      nu[0] = tot;
      ioff[tot] = (unsigned int)n;
    }
  }
  __syncthreads();
  unsigned int excP = exc2[0], excC = exc2[1];
  if (w < WORDS) {
    unsigned int rank = excP + ip - pres;   // exclusive presence prefix
    unsigned int coff = excC + ic - cnt;    // exclusive count prefix
    P[w] = mask; R[w] = rank;
    for (int j = 0; j < 64; j++) {
      unsigned int byte = (uu[j >> 2] >> (8 * (j & 3))) & 0xFFu;
      if (byte) {
        ioff[rank] = coff;
        unsigned int k = (unsigned int)w * 64u + (unsigned int)j;
        unsigned int x = k % NXc; unsigned int k2 = k / NXc;
        unsigned int y = k2 % NYc; unsigned int k3 = k2 / NYc;
        unsigned int z = k3 % NZc; unsigned int bb = k3 / NZc;
        outc[rank] = make_float4((float)bb, (float)z, (float)y, (float)x);
        rank++; coff += byte;
      }
    }
  }
}

// rank via bitmap popcount; intra-voxel slot via byte countdown on A.
__global__ void k_scatter(const int* __restrict__ keyPt, unsigned int* __restrict__ A32,
                          const unsigned long long* __restrict__ P, const unsigned int* __restrict__ R,
                          const unsigned int* __restrict__ ioff, unsigned int* __restrict__ pid, int n) {
  int p = blockIdx.x * 256 + threadIdx.x;
  if (p >= n) return;
  int key = keyPt[p];
  int w = key >> 6, bit = key & 63;
  unsigned int rank = R[w] + (unsigned int)__popcll(P[w] & ((1ull << bit) - 1ull));
  unsigned int sh = 8u * (unsigned int)(key & 3);
  unsigned int old = atomicSub(&A32[key >> 2], 1u << sh);
  unsigned int intra = ((old >> sh) & 0xFFu) - 1u;
  pid[ioff[rank] + intra] = (unsigned int)p;
}

// 16 lanes per row; RPT rows per lane-group, phase-split loads for MLP (G7).
__global__ void k_gather(const float4* __restrict__ pts, const unsigned int* __restrict__ pid,
                         const unsigned int* __restrict__ ioff, const unsigned int* __restrict__ nu,
                         float* __restrict__ out, int n) {
  int gt = blockIdx.x * 256 + threadIdx.x;
  int grp = gt >> 4, l = gt & 15;
  int rb = grp * RPT;
  if (rb >= n) return;
  unsigned int nU = nu[0];

  unsigned int e[RPT + 1];
#pragma unroll
  for (int j = 0; j <= RPT; j++) {
    unsigned int idx = min((unsigned int)(rb + j), nU);
    e[j] = ioff[idx];
  }

  unsigned int p0[RPT];
#pragma unroll
  for (int j = 0; j < RPT; j++)
    p0[j] = (e[j] < e[j + 1]) ? pid[e[j]] : 0u;

  float4 acc[RPT];
#pragma unroll
  for (int j = 0; j < RPT; j++) {
    if (e[j] < e[j + 1]) acc[j] = pts[(size_t)p0[j] * 16 + l];
    else                 acc[j] = make_float4(0.f, 0.f, 0.f, 0.f);
  }

#pragma unroll
  for (int j = 0; j < RPT; j++) {
    unsigned int span = e[j + 1] - e[j];
    for (unsigned int i = e[j] + 1; i < e[j + 1]; i++) {
      unsigned int p = pid[i];
      float4 v = pts[(size_t)p * 16 + l];
      acc[j].x += v.x; acc[j].y += v.y; acc[j].z += v.z; acc[j].w += v.w;
    }
    if (span > 1) {
      float inv = 1.0f / (float)span;
      acc[j].x *= inv; acc[j].y *= inv; acc[j].z *= inv; acc[j].w *= inv;
    }
  }

#pragma unroll
  for (int j = 0; j < RPT; j++) {
    int r = rb + j;
    if (r < n) ((float4*)out)[(size_t)r * 16 + l] = acc[j];
  }
}

extern "C" void kernel_launch(void* const* d_in, const int* in_sizes, int n_in,
                              void* d_out, int out_size, void* d_ws, size_t ws_size,
                              hipStream_t stream) {
  const float4* pts = (const float4*)d_in[0];   // points: float32 (1M x 64)
  const int4* coors = (const int4*)d_in[1];
  int n = in_sizes[1] / 4;  // 1,000,000
  float* out = (float*)d_out;                   // float32 output (68M elements)
  char* ws = (char*)d_ws;
  unsigned char*      A    = (unsigned char*)(ws + OFF_A);
  unsigned int*       A32  = (unsigned int*)(ws + OFF_A);
  unsigned long long* P    = (unsigned long long*)(ws + OFF_P);
  unsigned int*       R    = (unsigned int*)(ws + OFF_R);
  unsigned long long* desc = (unsigned long long*)(ws + OFF_DESC);
  unsigned int*       nu   = (unsigned int*)(ws + OFF_NU);
  int*                keyPt= (int*)(ws + OFF_KEYPT);
  unsigned int*       ioff = (unsigned int*)(ws + OFF_IOFF);
  unsigned int*       pid  = (unsigned int*)(ws + OFF_PID);
  float4*             outc = (float4*)(out + (size_t)n * NCH);

  k_zero   <<<2048,  256, 0, stream>>>((uint4*)A, (unsigned int)(KS / 16),
                                       (uint4*)desc, (unsigned int)(NBLKS * 8 / 16),
                                       outc, (unsigned int)n);
  int nb = (n + 255) / 256;
  k_count  <<<nb,    256, 0, stream>>>(coors, A32, keyPt, n);
  k_scan   <<<NBLKS, 256, 0, stream>>>(A, desc, P, R, ioff, nu, outc, n);
  k_scatter<<<nb,    256, 0, stream>>>(keyPt, A32, P, R, ioff, pid, n);
  int ngrp = (n + RPT - 1) / RPT;
  int gb = (ngrp * 16 + 255) / 256;
  k_gather <<<gb,    256, 0, stream>>>(pts, pid, ioff, nu, out, n);
}